// Round 5
// baseline (310.560 us; speedup 1.0000x reference)
//
#include <hip/hip_runtime.h>
#include <hip/hip_fp16.h>
#include <math.h>

#define NQ 14
#define NL 6
#define NT 1024
#define BATCH 1024
#define NGATES (NL * NQ)
#define NK 8     // half2 regs per re/im = 16 amps/thread
#define NCOEF 8  // 8 float matrix entries per gate (SGPR-friendly; convert at use)

// amp p = (tid<<4) | j, j=0..15. j bits 0-2 = reg k, j bit 3 = packing bit.
// storage bit map: 0-2 local k; 3 packing; 4-9 lane (tid bit p-4);
// 10-13 wave (tid bits 6-9). Wire w <-> amp bit P = 13-w.
//
// R24: occupancy doubling. Full state (64 KB LDS) is irreducible, so share
// it among 2x threads: NT 512->1024, NK 16->8. 2 blocks/CU stays, but now
// 32 waves/CU (100% cap) vs 16 — doubles latency hiding; per-thread chains
// halve. Layer structure unchanged from R22/23: phase A rots on storage
// bits 0..9 (wires 13..4, register/shuffle only), S-perm (bits 10-13 <->
// 0-3), phase B rots (wires 3..0 at bits 0..3), F_l∘S inter-layer perm.
// Last ring folded into measurement sign. Also: negated coeffs revert to
// R19-style precomputed bc(-m) (fp32 neg folds into v_cvt; R23's __hneg2
// did NOT fold into v_pk_fma modifiers -> +14% VALU issue).

using H2 = __half2;

__device__ __forceinline__ unsigned h2u(H2 v){ return __builtin_bit_cast(unsigned, v); }
__device__ __forceinline__ H2 u2h(unsigned x){ return __builtin_bit_cast(H2, x); }
__device__ __forceinline__ H2 bc(float x){ return __float2half2_rn(x); }
__device__ __forceinline__ H2 shflx(H2 v, int m){
    return u2h((unsigned)__shfl_xor((int)h2u(v), m, 64));
}

// image of index v under layer-l CNOT ring (gate order w=0..13) — GF(2)-linear
__device__ constexpr int ring_F(int l, int v) {
    int r = (l % 13) + 1;
    for (int w = 0; w < NQ; ++w) {
        int pc = 13 - w, pt = 13 - ((w + r) % NQ);
        v ^= ((v >> pc) & 1) << pt;
    }
    return v;
}
// swap storage bits 10,11,12,13 <-> 0,1,2,3 (involution)
__device__ constexpr int swapS(int v) {
    return (v & 0x03F0) | ((v & 15) << 10) | ((v >> 10) & 15);
}
// perm applied after phase B: mode<0 -> S (mid-layer), else F_mode∘S (inter-layer)
__device__ constexpr int pmapf(int mode, int v) {
    int u = swapS(v);
    return (mode < 0) ? u : ring_F(mode, u);
}
// measurement sign mask: bit13(F5(S(s))) = parity(s & M13)
__device__ constexpr int calc_m13() {
    int m = 0;
    for (int v = 0; v < NQ; ++v)
        if ((ring_F(NL - 1, swapS(1 << v)) >> 13) & 1) m |= 1 << v;
    return m;
}

// ---- swizzle correction: slot(a) = a ^ ((a>>4)&31) ^ gapply(G,(a>>9)&31)
// (modifies only bits 0-4 from bits >=4... bits 0-4 from higher bits ->
// bijective; GF(2)-linear). G: 5 columns x 5 bits (25-bit int).
__device__ constexpr int gapply(int G, int h) {
    int r = 0;
    for (int i = 0; i < 5; ++i) if ((h >> i) & 1) r ^= (G >> (5 * i)) & 31;
    return r;
}
__device__ constexpr int bank_vec(int mode, int G, int i) {
    int a = pmapf(mode, 1 << (4 + i));   // image of lane bit i (linear)
    return (a ^ (a >> 4) ^ gapply(G, (a >> 9) & 31)) & 31;
}
__device__ constexpr int pm_rank(int mode, int G) {
    int basis[5] = {0, 0, 0, 0, 0};
    int r = 0;
    for (int i = 0; i < 6; ++i) {
        int x = bank_vec(mode, G, i);
        for (int b = 4; b >= 0; --b) {
            if (((x >> b) & 1) == 0) continue;
            if (basis[b]) { x ^= basis[b]; }
            else { basis[b] = x; ++r; break; }
        }
    }
    return r;   // 5 => max 2 lanes/bank on the write scatter (free)
}
__device__ constexpr int find_g(int mode) {
    if (pm_rank(mode, 0) == 5) return 0;
    for (int col = 0; col < 5; ++col)
        for (int val = 1; val < 32; ++val) {
            int g = val << (5 * col);
            if (pm_rank(mode, g) == 5) return g;
        }
    for (int c1 = 0; c1 < 5; ++c1)
        for (int c2 = c1 + 1; c2 < 5; ++c2)
            for (int v1 = 1; v1 < 32; v1 <<= 1)
                for (int v2 = 1; v2 < 32; v2 <<= 1) {
                    int g = (v1 << (5 * c1)) | (v2 << (5 * c2));
                    if (pm_rank(mode, g) == 5) return g;
                }
    return 0;  // fallback: uncorrected swizzle (correct, maybe conflicted)
}

// ---- prep: Rot matrices (batch-shared, 8 floats/gate) into d_ws ----
__global__ void prep_kernel(const float* __restrict__ wts, float* __restrict__ gm) {
    int g = blockIdx.x * blockDim.x + threadIdx.x;
    if (g < NGATES) {
        float phi = wts[g*3+0], th = wts[g*3+1], om = wts[g*3+2];
        float c = cosf(0.5f*th), s = sinf(0.5f*th);
        float a = 0.5f*(phi+om), bb = 0.5f*(phi-om);
        float ca = cosf(a), sa = sinf(a);
        float cb = cosf(bb), sb = sinf(bb);
        gm[g*8+0] = c*ca;  gm[g*8+1] = -c*sa;   // m00
        gm[g*8+2] = -s*cb; gm[g*8+3] = -s*sb;   // m01
        gm[g*8+4] = s*cb;  gm[g*8+5] = -s*sb;   // m10
        gm[g*8+6] = c*ca;  gm[g*8+7] = c*sa;    // m11
    }
}

// ---- Rot on storage bit P (P <= 9: never touches LDS) ----
template<int P>
__device__ __forceinline__ void rot_gate(H2 (&pr)[NK], H2 (&pi)[NK],
                                         const float* __restrict__ m, int tid) {
    float m0=m[0],m1=m[1],m2=m[2],m3=m[3],m4=m[4],m5=m[5],m6=m[6],m7=m[7];
    if constexpr (P < 3) {
        constexpr int M = 1 << P;
        H2 h0=bc(m0),h1=bc(m1),nh1=bc(-m1),h2v=bc(m2),h3=bc(m3),nh3=bc(-m3);
        H2 h4=bc(m4),h5=bc(m5),nh5=bc(-m5),h6=bc(m6),h7=bc(m7),nh7=bc(-m7);
        #pragma unroll
        for (int i = 0; i < NK/2; ++i) {
            int k0 = ((i >> P) << (P+1)) | (i & (M-1));
            int k1 = k0 | M;
            H2 r0=pr[k0], i0=pi[k0], r1=pr[k1], i1=pi[k1];
            pr[k0] = __hfma2(h0,r0,__hfma2(nh1,i0,__hfma2(h2v,r1,__hmul2(nh3,i1))));
            pi[k0] = __hfma2(h0,i0,__hfma2(h1,r0,__hfma2(h2v,i1,__hmul2(h3,r1))));
            pr[k1] = __hfma2(h4,r0,__hfma2(nh5,i0,__hfma2(h6,r1,__hmul2(nh7,i1))));
            pi[k1] = __hfma2(h4,i0,__hfma2(h5,r0,__hfma2(h6,i1,__hmul2(h7,r1))));
        }
    } else if constexpr (P == 3) {
        // packing-bit rot: half-swap + per-half coeff H2s
        H2 cAr = __floats2half2_rn(m0, m6), cAi = __floats2half2_rn(m1, m7);
        H2 nAi = __floats2half2_rn(-m1,-m7);
        H2 cBr = __floats2half2_rn(m2, m4), cBi = __floats2half2_rn(m3, m5);
        H2 nBi = __floats2half2_rn(-m3,-m5);
        #pragma unroll
        for (int k = 0; k < NK; ++k) {
            unsigned Ar = h2u(pr[k]), Ai = h2u(pi[k]);
            H2 sr = u2h((Ar>>16)|(Ar<<16)), si = u2h((Ai>>16)|(Ai<<16));
            H2 r = pr[k], i = pi[k];
            pr[k] = __hfma2(cAr,r,__hfma2(nAi,i,__hfma2(cBr,sr,__hmul2(nBi,si))));
            pi[k] = __hfma2(cAr,i,__hfma2(cAi,r,__hfma2(cBr,si,__hmul2(cBi,sr))));
        }
    } else {
        constexpr int LM = 1 << (P-4);
        int bit = (tid >> (P-4)) & 1;
        float cAr = bit ? m6 : m0, cAi = bit ? m7 : m1;
        float cBr = bit ? m4 : m2, cBi = bit ? m5 : m3;
        H2 a=bc(cAr), ai2=bc(cAi), nai=bc(-cAi), b2=bc(cBr), bi2=bc(cBi), nbi=bc(-cBi);
        #pragma unroll
        for (int k = 0; k < NK; ++k) {
            H2 r = pr[k], i = pi[k];
            H2 qr = shflx(r, LM), qi = shflx(i, LM);
            pr[k] = __hfma2(a,r,__hfma2(nai,i,__hfma2(b2,qr,__hmul2(nbi,qi))));
            pi[k] = __hfma2(a,i,__hfma2(ai2,r,__hfma2(b2,qi,__hmul2(bi2,qr))));
        }
    }
}

// ---- one GF(2)-linear LDS permutation (scatter write, swizzled read) ----
// slot(a) = a ^ ((a>>4)&31) ^ gapply(G,(a>>9)&31); G chosen at compile time
// so the write-side lane->bank map has rank 5 (2-way max = free). Read side
// is exactly 2-way for any G (lane-bit bank map: e0^e4,e1,e2,e3,e4,G-col).
// Barriers: entry + mid; no trailing barrier. Opaque-tid stops the 11 perm
// address nets being CSE-hoisted to kernel entry (R22: +~15 VGPR).
template<int MODE>
__device__ __forceinline__ void perm_exchange(H2 (&pr)[NK], H2 (&pi)[NK],
                                              int tid, unsigned* ub) {
    constexpr int G = find_g(MODE);
    int t = tid;
    asm volatile("" : "+v"(t));
    int base = pmapf(MODE, t << 4);   // linear: M(p) = M(tid<<4) ^ M(j)
    int gbase = gapply(G, (base >> 9) & 31);
    __syncthreads();
    #pragma unroll
    for (int k = 0; k < NK; ++k) {
        unsigned wlo = (h2u(pr[k]) & 0xFFFFu) | (h2u(pi[k]) << 16);      // amp j=k
        unsigned whi = (h2u(pr[k]) >> 16) | (h2u(pi[k]) & 0xFFFF0000u);  // amp j=k|8
        int flo = base ^ pmapf(MODE, k);        // pmapf/gapply of k fold to consts
        int fhi = base ^ pmapf(MODE, k | 8);
        int alo = flo ^ ((flo >> 4) & 31) ^ gbase ^ gapply(G, (pmapf(MODE, k) >> 9) & 31);
        int ahi = fhi ^ ((fhi >> 4) & 31) ^ gbase ^ gapply(G, (pmapf(MODE, k | 8) >> 9) & 31);
        ub[alo] = wlo;
        ub[ahi] = whi;
    }
    __syncthreads();
    int grd = (t & 31) ^ gapply(G, (t >> 5) & 31);   // read: slot(tid<<4|j)
    #pragma unroll
    for (int k = 0; k < NK; ++k) {
        unsigned wlo = ub[((t << 4) | k) ^ grd];
        unsigned whi = ub[((t << 4) | (k | 8)) ^ grd];
        pr[k] = u2h((wlo & 0xFFFFu) | (whi << 16));
        pi[k] = u2h((wlo >> 16) | (whi & 0xFFFF0000u));
    }
}

// ---- compile-time circuit drivers ----
template<int L, int P>
__device__ __forceinline__ void do_rotsA(H2 (&pr)[NK], H2 (&pi)[NK],
                                         const float* __restrict__ gm, int tid) {
    rot_gate<P>(pr, pi, gm + (L*NQ + (13-P))*NCOEF, tid);   // wire 13-P at bit P
    if constexpr (P < 9) do_rotsA<L, P+1>(pr, pi, gm, tid);
}

template<int L>
__device__ __forceinline__ void do_layer(H2 (&pr)[NK], H2 (&pi)[NK],
                                         const float* __restrict__ gm, int tid,
                                         unsigned* ub) {
    do_rotsA<L, 0>(pr, pi, gm, tid);          // wires 13..4
    perm_exchange<-1>(pr, pi, tid, ub);       // S: bits 10-13 <-> 0-3
    rot_gate<0>(pr, pi, gm + (L*NQ + 3)*NCOEF, tid);  // wire 3 now at bit 0
    rot_gate<1>(pr, pi, gm + (L*NQ + 2)*NCOEF, tid);  // wire 2 at bit 1
    rot_gate<2>(pr, pi, gm + (L*NQ + 1)*NCOEF, tid);  // wire 1 at bit 2
    rot_gate<3>(pr, pi, gm + (L*NQ + 0)*NCOEF, tid);  // wire 0 at bit 3 (packing)
    if constexpr (L < NL-1) {
        perm_exchange<L>(pr, pi, tid, ub);    // F_L ∘ S: ring + back to canonical
        do_layer<L+1>(pr, pi, gm, tid, ub);
    }
    // last layer: ring folded into measurement sign
}

__global__ void __launch_bounds__(NT, 8)
qsim_kernel(
    const float* __restrict__ x,
    const float* __restrict__ gm,
    float* __restrict__ out)
{
    __shared__ unsigned ub[16384];   // 64 KB -> 2 blocks/CU, now 32 waves/CU
    const int tid = threadIdx.x;
    const int b = blockIdx.x;
    const float* xb = x + b * NQ;

    // ---- direct product-state init (fp32 math, pack to fp16) ----
    H2 pr[NK], pi[NK];
    {
        float cr = 1.f, ci = 0.f;
        #pragma unroll
        for (int bb = 0; bb < 10; ++bb) {      // tid bit bb = amp bit 4+bb = wire 9-bb
            float s, c; __sincosf(0.5f * xb[9 - bb], &s, &c);
            if ((tid >> bb) & 1) { float nr = s*ci, ni = -s*cr; cr = nr; ci = ni; }
            else                 { cr *= c; ci *= c; }
        }
        float lc[3], ls[3];                     // k bit bb = amp bit bb = wire 13-bb
        #pragma unroll
        for (int bb = 0; bb < 3; ++bb) __sincosf(0.5f * xb[13 - bb], &ls[bb], &lc[bb]);
        float sP, cP; __sincosf(0.5f * xb[10], &sP, &cP);  // packing bit = wire 10
        #pragma unroll
        for (int k = 0; k < NK; ++k) {
            float rr = cr, ii = ci;
            #pragma unroll
            for (int bb = 0; bb < 3; ++bb) {
                if ((k >> bb) & 1) { float nr = ls[bb]*ii, ni = -ls[bb]*rr; rr = nr; ii = ni; }
                else               { rr *= lc[bb]; ii *= lc[bb]; }
            }
            pr[k] = __floats2half2_rn(rr*cP,  sP*ii);
            pi[k] = __floats2half2_rn(ii*cP, -sP*rr);
        }
    }

    do_layer<0>(pr, pi, gm, tid, ub);

    // ---- <Z0>: state is in layout S; sign = bit13(F5(S(s))) = parity(s&M13) ----
    constexpr int M13 = calc_m13();
    int tpar = __builtin_popcount((tid << 4) & M13) & 1;
    float acc = 0.f;
    #pragma unroll
    for (int k = 0; k < NK; ++k) {
        float a=__low2float(pr[k]), c=__high2float(pr[k]);
        float d=__low2float(pi[k]), e=__high2float(pi[k]);
        float vlo = a*a + d*d, vhi = c*c + e*e;
        int slo = tpar ^ (__builtin_popcount(k & M13) & 1);          // folds per k
        int shi = tpar ^ (__builtin_popcount((k | 8) & M13) & 1);
        acc += slo ? -vlo : vlo;
        acc += shi ? -vhi : vhi;
    }
    #pragma unroll
    for (int off = 32; off > 0; off >>= 1) acc += __shfl_down(acc, off, 64);
    __syncthreads();   // all waves' perm reads done before ub reuse
    float* f = (float*)ub;
    if ((tid & 63) == 0) f[tid >> 6] = acc;
    __syncthreads();
    if (tid == 0) {
        float s = 0.f;
        #pragma unroll
        for (int w = 0; w < NT/64; ++w) s += f[w];
        out[b] = s;
    }
}

extern "C" void kernel_launch(void* const* d_in, const int* in_sizes, int n_in,
                              void* d_out, int out_size, void* d_ws, size_t ws_size,
                              hipStream_t stream) {
    const float* x = (const float*)d_in[0];   // (1024, 14) float32
    const float* w = (const float*)d_in[1];   // (6, 14, 3) float32
    float* out = (float*)d_out;               // (1024,) float32
    float* gm = (float*)d_ws;                 // 84*8 floats of Rot matrices

    prep_kernel<<<1, 128, 0, stream>>>(w, gm);
    qsim_kernel<<<BATCH, NT, 0, stream>>>(x, gm, out);
}

// Round 6
// 219.513 us; speedup vs baseline: 1.4148x; 1.4148x over previous
//
#include <hip/hip_runtime.h>
#include <hip/hip_fp16.h>
#include <math.h>

#define NQ 14
#define NL 6
#define NT 512
#define BATCH 1024
#define NGATES (NL * NQ)

// R25: move ALL gate math onto the (idle) MFMA pipe.
// State: 16384 complex amps in LDS, f16 PLANAR (re[16384], im[16384]).
// Per layer, 3 fused-gate matmuls ("applies"):
//   apply0: wires 4..0  (amp bits 9-13), 32x32 complex = 64x64 real, K=64,N=64
//   apply1: wires 9..5  (amp bits 4-8),  same shape
//   apply2: wires 13..10 (amp bits 0-3), 16x16 complex = 32x32 real, K=32,N=32
// Real expansion (planar): A = [re | im] along K; B = [[Gr,Gi],[-Gi,Gr]];
// D = [re | im] along N. mfma_f32_32x32x16_f16, f32 accumulation.
// Between applies the "regroup" is free: each window has its own GF(2)-linear
// amp->addr map (pi0/pi1/pi2) chosen so A-reads are contiguous b128 and
// D-writes pack b64 (XOR bits 3/4 fix bank spread). The layer's CNOT ring
// folds into apply2's write map pi0(ring_F(L,amp)) — linear, constexpr.
// Measurement: state ends in pi0 layout post-ring; sign = amp13 recovered
// via the constexpr inverse mask of pi0.
// Fragment layout commitments (gfx950 mfma_f32_32x32x16_f16):
//   A: lane row = l&31, k = 8*(l>>5)+e   (standard CDNA mapping)
//   B: lane col = l&31, k = 8*(l>>5)+e
//   D: col = l&31, row = (reg&3)+8*(reg>>2)+4*(l>>5)   (HW-verified)

typedef _Float16 half8 __attribute__((ext_vector_type(8)));
typedef float f32x16 __attribute__((ext_vector_type(16)));

// ---- CNOT ring of layer l: image of index v (GF(2)-linear) ----
__device__ constexpr int ring_F(int l, int v) {
    int r = (l % 13) + 1;
    for (int w = 0; w < NQ; ++w) {
        int pc = 13 - w, pt = 13 - ((w + r) % NQ);
        v ^= ((v >> pc) & 1) << pt;
    }
    return v;
}

// ---- window maps: amp index -> u16 addr within a 16384-entry plane ----
// pi0: read by apply0 (k = amp9-13). b0-2 = a9,a10,a11 (b128 contiguity).
__device__ constexpr int pi0(int a) {
    int b = ((a >> 9) & 7)
          | (((a >> 12) & 1) << 3) | (((a >> 13) & 1) << 4)
          | (((a >> 4) & 31) << 5)        // b5-9  = a4..a8
          | ((a & 15) << 10);             // b10-13 = a0..a3
    b ^= ((((a >> 7) & 1) ^ (a & 1)) << 3);        // b3 ^= a7 ^ a0
    b ^= ((((a >> 8) & 1) ^ ((a >> 1) & 1)) << 4); // b4 ^= a8 ^ a1
    return b;
}
// pi1: read by apply1 (k = amp4-8).
__device__ constexpr int pi1(int a) {
    int b = ((a >> 4) & 7)
          | (((a >> 7) & 1) << 3) | (((a >> 8) & 1) << 4)
          | ((a & 15) << 5)               // b5-8 = a0..a3
          | (((a >> 9) & 31) << 9);       // b9-13 = a9..a13
    b ^= ((((a >> 3) & 1) ^ ((a >> 10) & 1)) << 3); // b3 ^= a3 ^ a10
    b ^= ((((a >> 9) & 1) ^ ((a >> 11) & 1)) << 4); // b4 ^= a9 ^ a11
    return b;
}
// pi2: read by apply2 (k = amp0-3).
__device__ constexpr int pi2(int a) {
    int b = (a & 7)
          | (((a >> 3) & 1) << 3)
          | (((a >> 9) & 31) << 4)        // b4-8 = a9..a13
          | (((a >> 4) & 31) << 9);       // b9-13 = a4..a8
    b ^= (((a >> 4) & 1) << 3);   // b3 ^= a4
    b ^= (((a >> 5) & 1) << 4);   // b4 ^= a5
    b ^= (((a >> 6) & 1) << 5);   // b5 ^= a6
    b ^= (((a >> 7) & 1) << 6);   // b6 ^= a7
    return b;
}
// sign mask: parity(addr & SGN) == bit13 of pi0^-1(addr) (amp13 = wire 0)
__device__ constexpr int sgn_mask() {
    int m = 0;
    for (int p = 0; p < 14; ++p)
        for (int a = 0; a < 16384; ++a)
            if (pi0(a) == (1 << p)) { if ((a >> 13) & 1) m |= 1 << p; break; }
    return m;
}

// ---- prep1: per-gate 2x2 complex Rot matrices (re,im per entry) ----
__global__ void prep_kernel(const float* __restrict__ wts, float* __restrict__ gm) {
    int g = blockIdx.x * blockDim.x + threadIdx.x;
    if (g < NGATES) {
        float phi = wts[g*3+0], th = wts[g*3+1], om = wts[g*3+2];
        float c = cosf(0.5f*th), s = sinf(0.5f*th);
        float a = 0.5f*(phi+om), bb = 0.5f*(phi-om);
        float ca = cosf(a), sa = sinf(a);
        float cb = cosf(bb), sb = sinf(bb);
        gm[g*8+0] = c*ca;  gm[g*8+1] = -c*sa;   // m00
        gm[g*8+2] = -s*cb; gm[g*8+3] = -s*sb;   // m01
        gm[g*8+4] = s*cb;  gm[g*8+5] = -s*sb;   // m10
        gm[g*8+6] = c*ca;  gm[g*8+7] = c*sa;    // m11
    }
}

// ---- prep2: fused group matrices in B-fragment layout ----
// frag ids per layer: apply0: 0-7 (t*4+m), apply1: 8-15, apply2: 16-17 (m)
// element: B[k-real][n-real]; value from G = tensor-product of 2x2 rots.
__global__ void prep2_kernel(const float* __restrict__ gm, _Float16* __restrict__ B) {
    int t = blockIdx.x * blockDim.x + threadIdx.x;
    if (t >= NL * 18 * 64) return;
    int lane = t & 63;
    int fi = (t >> 6) % 18;
    int L = t / (18 * 64);
    int a, tt, m;
    if (fi < 8)       { a = 0; tt = fi >> 2;        m = fi & 3; }
    else if (fi < 16) { a = 1; tt = (fi - 8) >> 2;  m = (fi - 8) & 3; }
    else              { a = 2; tt = 0;              m = fi - 16; }
    int h = lane >> 5, c = lane & 31;
    for (int e = 0; e < 8; ++e) {
        int kc, kp, nc, np, nb;
        if (a < 2) { int kr = 16*m + 8*h + e; int nr = 32*tt + c;
                     kc = kr & 31; kp = kr >> 5; nc = nr & 31; np = nr >> 5; nb = 5; }
        else       { kc = 8*h + e; kp = m; nc = c & 15; np = c >> 4; nb = 4; }
        float gr = 1.f, gi = 0.f;
        for (int j = 0; j < nb; ++j) {
            int w = (a == 0) ? (4 - j) : (a == 1) ? (9 - j) : (13 - j);
            const float* mm = gm + (L*NQ + w)*8;
            const float* ent = mm + (((nc >> j) & 1) * 2 + ((kc >> j) & 1)) * 2;
            float er = ent[0], ei = ent[1];
            float ngr = gr*er - gi*ei, ngi = gr*ei + gi*er;
            gr = ngr; gi = ngi;
        }
        float v = (kp == np) ? gr : (kp ? -gi : gi);
        B[((L*18 + fi)*64 + lane)*8 + e] = (_Float16)v;
    }
}

// ---- the three applies ----
template<int L>
__device__ __forceinline__ void apply0(_Float16* st, const _Float16* B, int lane, int wid) {
    const int h = lane >> 5, l31 = lane & 31;
    half8 Bf[8];
    #pragma unroll
    for (int f = 0; f < 8; ++f)
        Bf[f] = *(const half8*)(B + ((L*18 + f)*64 + lane)*8);
    half8 Af[2][4];
    #pragma unroll
    for (int ss = 0; ss < 2; ++ss) {
        int s = wid*2 + ss;
        int base = pi0((l31 << 4) | s | (h << 12));
        #pragma unroll
        for (int m = 0; m < 4; ++m)
            Af[ss][m] = *(const half8*)(st + (base ^ (((m & 1) << 4) | ((m >> 1) << 14))));
    }
    __syncthreads();
    #pragma unroll
    for (int ss = 0; ss < 2; ++ss) {
        int s = wid*2 + ss;
        int wb = pi1((l31 << 9) | s | (h << 6));
        #pragma unroll
        for (int t = 0; t < 2; ++t) {
            f32x16 acc;
            #pragma unroll
            for (int j = 0; j < 16; ++j) acc[j] = 0.f;
            #pragma unroll
            for (int m = 0; m < 4; ++m)
                acc = __builtin_amdgcn_mfma_f32_32x32x16_f16(Af[ss][m], Bf[t*4+m], acc, 0, 0, 0);
            #pragma unroll
            for (int q = 0; q < 4; ++q) {
                uint2 w;
                w.x = __builtin_bit_cast(unsigned, __builtin_amdgcn_cvt_pkrtz(acc[4*q+0], acc[4*q+1]));
                w.y = __builtin_bit_cast(unsigned, __builtin_amdgcn_cvt_pkrtz(acc[4*q+2], acc[4*q+3]));
                int wa = wb ^ ((q & 1) << 3) ^ ((q >> 1) << 4) ^ (t << 14);
                *(uint2*)(st + wa) = w;
            }
        }
    }
    __syncthreads();
}

template<int L>
__device__ __forceinline__ void apply1(_Float16* st, const _Float16* B, int lane, int wid) {
    const int h = lane >> 5, l31 = lane & 31;
    half8 Bf[8];
    #pragma unroll
    for (int f = 0; f < 8; ++f)
        Bf[f] = *(const half8*)(B + ((L*18 + 8 + f)*64 + lane)*8);
    half8 Af[2][4];
    #pragma unroll
    for (int ss = 0; ss < 2; ++ss) {
        int s = wid*2 + ss;
        int base = pi1((l31 & 15) | ((l31 >> 4) << 9) | (s << 10) | (h << 7));
        #pragma unroll
        for (int m = 0; m < 4; ++m)
            Af[ss][m] = *(const half8*)(st + (base ^ (((m & 1) << 4) | ((m >> 1) << 14))));
    }
    __syncthreads();
    #pragma unroll
    for (int ss = 0; ss < 2; ++ss) {
        int s = wid*2 + ss;
        int wb = pi2((l31 << 4) | (h << 2) | (s << 10));
        #pragma unroll
        for (int t = 0; t < 2; ++t) {
            f32x16 acc;
            #pragma unroll
            for (int j = 0; j < 16; ++j) acc[j] = 0.f;
            #pragma unroll
            for (int m = 0; m < 4; ++m)
                acc = __builtin_amdgcn_mfma_f32_32x32x16_f16(Af[ss][m], Bf[t*4+m], acc, 0, 0, 0);
            #pragma unroll
            for (int q = 0; q < 4; ++q) {
                uint2 w;
                w.x = __builtin_bit_cast(unsigned, __builtin_amdgcn_cvt_pkrtz(acc[4*q+0], acc[4*q+1]));
                w.y = __builtin_bit_cast(unsigned, __builtin_amdgcn_cvt_pkrtz(acc[4*q+2], acc[4*q+3]));
                int wa = wb ^ ((q & 1) << 3) ^ ((q >> 1) << 4) ^ (t << 14);
                *(uint2*)(st + wa) = w;
            }
        }
    }
    __syncthreads();
}

template<int L>
__device__ __forceinline__ void apply2(_Float16* st, const _Float16* B, int lane, int wid) {
    const int h = lane >> 5, l31 = lane & 31;
    half8 Bf[2];
    #pragma unroll
    for (int f = 0; f < 2; ++f)
        Bf[f] = *(const half8*)(B + ((L*18 + 16 + f)*64 + lane)*8);
    half8 Af[4][2];
    #pragma unroll
    for (int ss = 0; ss < 4; ++ss) {
        int s = wid*4 + ss;
        int base = pi2((l31 << 9) | (s << 4) | (h << 3));
        Af[ss][0] = *(const half8*)(st + base);
        Af[ss][1] = *(const half8*)(st + (base ^ 16384));
    }
    __syncthreads();
    // ring fold: write amp p's output at pi0(F_L(p)); per-element b16 scatter
    constexpr int D9  = pi0(ring_F(L, 1 << 9));
    constexpr int D10 = pi0(ring_F(L, 1 << 10));
    constexpr int D12 = pi0(ring_F(L, 1 << 12));
    constexpr int D13 = pi0(ring_F(L, 1 << 13));
    #pragma unroll
    for (int ss = 0; ss < 4; ++ss) {
        int s = wid*4 + ss;
        int wb = pi0(ring_F(L, (l31 & 15) | (s << 4) | (h << 11))) ^ ((l31 >> 4) << 14);
        f32x16 acc;
        #pragma unroll
        for (int j = 0; j < 16; ++j) acc[j] = 0.f;
        acc = __builtin_amdgcn_mfma_f32_32x32x16_f16(Af[ss][0], Bf[0], acc, 0, 0, 0);
        acc = __builtin_amdgcn_mfma_f32_32x32x16_f16(Af[ss][1], Bf[1], acc, 0, 0, 0);
        #pragma unroll
        for (int r = 0; r < 16; ++r) {
            int wa = wb ^ ((r & 1) ? D9 : 0) ^ ((r & 2) ? D10 : 0)
                        ^ ((r & 4) ? D12 : 0) ^ ((r & 8) ? D13 : 0);
            st[wa] = (_Float16)acc[r];
        }
    }
    __syncthreads();
}

template<int L>
__device__ __forceinline__ void do_layer(_Float16* st, const _Float16* B, int lane, int wid) {
    apply0<L>(st, B, lane, wid);
    apply1<L>(st, B, lane, wid);
    apply2<L>(st, B, lane, wid);
    if constexpr (L < NL - 1) do_layer<L+1>(st, B, lane, wid);
}

__global__ void __launch_bounds__(NT, 4)
qsim_kernel(const float* __restrict__ x, const _Float16* __restrict__ B,
            float* __restrict__ out)
{
    __shared__ _Float16 st[32768];   // re plane [0,16384), im plane [16384,32768)
    const int tid = threadIdx.x;
    const int lane = tid & 63, wid = tid >> 6;
    const int b = blockIdx.x;
    const float* xb = x + b * NQ;

    // ---- product-state init: thread bits -> amp bits 5-13, i -> amp 0-4 ----
    {
        float cr = 1.f, ci = 0.f;
        #pragma unroll
        for (int bb = 0; bb < 9; ++bb) {      // amp bit 5+bb = wire 8-bb
            float s, c; __sincosf(0.5f * xb[8 - bb], &s, &c);
            if ((tid >> bb) & 1) { float nr = s*ci, ni = -s*cr; cr = nr; ci = ni; }
            else                 { cr *= c; ci *= c; }
        }
        float lc[5], ls[5];                   // amp bit bb = wire 13-bb
        #pragma unroll
        for (int bb = 0; bb < 5; ++bb) __sincosf(0.5f * xb[13 - bb], &ls[bb], &lc[bb]);
        int pb = pi0(tid << 5);
        #pragma unroll
        for (int i = 0; i < 32; ++i) {
            float rr = cr, ii = ci;
            #pragma unroll
            for (int bb = 0; bb < 5; ++bb) {
                if ((i >> bb) & 1) { float nr = ls[bb]*ii, ni = -ls[bb]*rr; rr = nr; ii = ni; }
                else               { rr *= lc[bb]; ii *= lc[bb]; }
            }
            int a = pb ^ pi0(i);
            st[a]         = (_Float16)rr;
            st[a + 16384] = (_Float16)ii;
        }
    }
    __syncthreads();

    do_layer<0>(st, B, lane, wid);

    // ---- <Z0>: state in pi0 layout (post-ring); sign = amp13 via SGN ----
    constexpr int SGN = sgn_mask();
    float acc = 0.f;
    int base = tid * 32;
    #pragma unroll
    for (int c = 0; c < 4; ++c) {
        half8 re = *(const half8*)(st + base + c*8);
        half8 im = *(const half8*)(st + 16384 + base + c*8);
        int sg = __builtin_popcount((base + c*8) & SGN) & 1;  // SGN&7==0
        #pragma unroll
        for (int e = 0; e < 8; ++e) {
            float r = (float)re[e], iv = (float)im[e];
            float v = r*r + iv*iv;
            acc += sg ? -v : v;
        }
    }
    #pragma unroll
    for (int off = 32; off > 0; off >>= 1) acc += __shfl_down(acc, off, 64);
    __syncthreads();
    float* f = (float*)st;
    if ((tid & 63) == 0) f[tid >> 6] = acc;
    __syncthreads();
    if (tid == 0) {
        float s = 0.f;
        #pragma unroll
        for (int w = 0; w < NT/64; ++w) s += f[w];
        out[b] = s;
    }
}

extern "C" void kernel_launch(void* const* d_in, const int* in_sizes, int n_in,
                              void* d_out, int out_size, void* d_ws, size_t ws_size,
                              hipStream_t stream) {
    const float* x = (const float*)d_in[0];   // (1024, 14) float32
    const float* w = (const float*)d_in[1];   // (6, 14, 3) float32
    float* out = (float*)d_out;               // (1024,) float32
    float* gm = (float*)d_ws;                 // 84*8 floats of 2x2 rot matrices
    _Float16* B = (_Float16*)((char*)d_ws + 4096);  // 6*18*64*8 halfs of B-frags

    prep_kernel<<<1, 128, 0, stream>>>(w, gm);
    prep2_kernel<<<27, 256, 0, stream>>>(gm, B);
    qsim_kernel<<<BATCH, NT, 0, stream>>>(x, B, out);
}

// Round 7
// 146.545 us; speedup vs baseline: 2.1192x; 1.4979x over previous
//
#include <hip/hip_runtime.h>
#include <hip/hip_fp16.h>
#include <math.h>

#define NQ 14
#define NL 6
#define NT 512
#define BATCH 1024
#define NGATES (NL * NQ)
#define GINIT 0x111   // base correction: a0->c0, a1->c1, a2->c2

// R26: R25's MFMA engine (verified) + bank-conflict-derived address maps.
// State: 16384 complex amps, f16 planar in one 64KB LDS buffer.
// Window j transforms amp-group g_j: g0=bits9-13, g1=bits4-8, g2=bits0-3.
// Layout Lam_j: addr = e(3b: g_j b0-2) | chunk<<3.
//   Lam0 chunk: c0-4=g1, c5=a12, c6=a13, c7=p, c8-11=g2, c0-2 ^= G-corr(a0-3,p)
//   Lam1 chunk: c0-3=g2, c4=a13, c5=a7, c6=a8, c7=p, c8=a12, c9-11=a9-11, c0-2^=a9-11
//   Lam2 chunk: c0-4=g0, c5=a3, c6=p, c7-8=a7-8, c9-11=a4-6, c0-2^=a4-6
// Invariants (derived, GF(2) lane->bank rank checked):
//  - A-reads: one b128/lane, 64 distinct chunks, chunk&7 = lane&7 -> optimal.
//  - D-writes: aligned b64 (window j's M-rows = g_{j+1} exactly: mr0-1 ->
//    addr b0-1, h' -> b2, q -> k-high bits). Bank-pairs: 16 x 4 lanes = free,
//    because each layout XORs the writer's lane-varying n0-2 into chunk b0-2.
//  - apply2's ring-folded b16 scatter: per-layer constexpr search over the
//    G family (keys {a0-3,p} -> chunk b0-2) maximizes lane->bank rank (5 =
//    2 lanes/bank = free). Reads are immune to any G (keys are read-fixed).
// mfma_f32_32x32x16_f16; A: row=l&31, k=8*(l>>5)+e; D: col=l&31,
// row=(reg&3)+8*(reg>>2)+4*(l>>5) (hardware-verified by R25 passing).

typedef _Float16 half8 __attribute__((ext_vector_type(8)));
typedef float f32x16 __attribute__((ext_vector_type(16)));

__device__ constexpr int ring_F(int l, int v) {
    int r = (l % 13) + 1;
    for (int w = 0; w < NQ; ++w) {
        int pc = 13 - w, pt = 13 - ((w + r) % NQ);
        v ^= ((v >> pc) & 1) << pt;
    }
    return v;
}

// correction: keys (a0,a1,a2,a3,p) -> chunk bits 0-2; G bit (3k+t)
__device__ constexpr int gcorr(int G, int a, int p) {
    int keys = (a & 15) | ((p & 1) << 4);
    int c = 0;
    for (int k = 0; k < 5; ++k) if ((keys >> k) & 1) c ^= (G >> (3 * k)) & 7;
    return c;
}
__device__ constexpr int lam0(int a, int p, int G) {
    int chunk = ((a >> 4) & 31) | (((a >> 12) & 1) << 5) | (((a >> 13) & 1) << 6)
              | ((p & 1) << 7) | ((a & 15) << 8);
    chunk ^= gcorr(G, a, p);
    return ((a >> 9) & 7) | (chunk << 3);
}
__device__ constexpr int lam1(int a, int p) {
    int chunk = (a & 15) | (((a >> 13) & 1) << 4) | (((a >> 7) & 1) << 5)
              | (((a >> 8) & 1) << 6) | ((p & 1) << 7) | (((a >> 12) & 1) << 8)
              | (((a >> 9) & 7) << 9);
    chunk ^= (a >> 9) & 7;
    return ((a >> 4) & 7) | (chunk << 3);
}
__device__ constexpr int lam2(int a, int p) {
    int chunk = ((a >> 9) & 31) | (((a >> 3) & 1) << 5) | ((p & 1) << 6)
              | (((a >> 7) & 3) << 7) | (((a >> 4) & 7) << 9);
    chunk ^= (a >> 4) & 7;
    return (a & 7) | (chunk << 3);
}

__device__ constexpr int vrank5(int v0, int v1, int v2, int v3, int v4, int v5) {
    int vs[6] = {v0, v1, v2, v3, v4, v5};
    int basis[5] = {0, 0, 0, 0, 0};
    int r = 0;
    for (int i = 0; i < 6; ++i) {
        int x = vs[i];
        for (int b = 4; b >= 0; --b) {
            if (((x >> b) & 1) == 0) continue;
            if (basis[b]) { x ^= basis[b]; }
            else { basis[b] = x; ++r; break; }
        }
    }
    return r;
}
// lane->bank (addr bits 1-5) rank of apply2's b16 scatter into Lam0^G.
// lane deltas: l0-3 -> u0-3 (new g2), l4 -> plane, l5 -> u11 (h'=mr2).
__device__ constexpr int scat_rank(int L, int G) {
    return vrank5(
        (lam0(ring_F(L, 1), 0, G) >> 1) & 31,
        (lam0(ring_F(L, 2), 0, G) >> 1) & 31,
        (lam0(ring_F(L, 4), 0, G) >> 1) & 31,
        (lam0(ring_F(L, 8), 0, G) >> 1) & 31,
        (lam0(0, 1, G) >> 1) & 31,
        (lam0(ring_F(L, 1 << 11), 0, G) >> 1) & 31);
}
__device__ constexpr int find_g0(int L) {
    if (scat_rank(L, GINIT) == 5) return GINIT;
    for (int s = 0; s < 15; ++s)
        if (scat_rank(L, GINIT ^ (1 << s)) == 5) return GINIT ^ (1 << s);
    for (int s1 = 0; s1 < 15; ++s1)
        for (int s2 = s1 + 1; s2 < 15; ++s2)
            if (scat_rank(L, GINIT ^ (1 << s1) ^ (1 << s2)) == 5)
                return GINIT ^ (1 << s1) ^ (1 << s2);
    int best = GINIT, br = scat_rank(L, GINIT);
    for (int s = 0; s < 15; ++s) {
        int g = GINIT ^ (1 << s);
        int rr = scat_rank(L, g);
        if (rr > br) { best = g; br = rr; }
    }
    return best;
}
__device__ constexpr int gsrc(int L) { return L < 0 ? GINIT : find_g0(L); }

// ---- prep1: per-gate 2x2 complex Rot matrices ----
__global__ void prep_kernel(const float* __restrict__ wts, float* __restrict__ gm) {
    int g = blockIdx.x * blockDim.x + threadIdx.x;
    if (g < NGATES) {
        float phi = wts[g*3+0], th = wts[g*3+1], om = wts[g*3+2];
        float c = cosf(0.5f*th), s = sinf(0.5f*th);
        float a = 0.5f*(phi+om), bb = 0.5f*(phi-om);
        float ca = cosf(a), sa = sinf(a);
        float cb = cosf(bb), sb = sinf(bb);
        gm[g*8+0] = c*ca;  gm[g*8+1] = -c*sa;   // m00
        gm[g*8+2] = -s*cb; gm[g*8+3] = -s*sb;   // m01
        gm[g*8+4] = s*cb;  gm[g*8+5] = -s*sb;   // m10
        gm[g*8+6] = c*ca;  gm[g*8+7] = c*sa;    // m11
    }
}

// ---- prep2: fused group matrices in B-fragment layout (unchanged R25) ----
__global__ void prep2_kernel(const float* __restrict__ gm, _Float16* __restrict__ B) {
    int t = blockIdx.x * blockDim.x + threadIdx.x;
    if (t >= NL * 18 * 64) return;
    int lane = t & 63;
    int fi = (t >> 6) % 18;
    int L = t / (18 * 64);
    int a, tt, m;
    if (fi < 8)       { a = 0; tt = fi >> 2;        m = fi & 3; }
    else if (fi < 16) { a = 1; tt = (fi - 8) >> 2;  m = (fi - 8) & 3; }
    else              { a = 2; tt = 0;              m = fi - 16; }
    int h = lane >> 5, c = lane & 31;
    for (int e = 0; e < 8; ++e) {
        int kc, kp, nc, np, nb;
        if (a < 2) { int kr = 16*m + 8*h + e; int nr = 32*tt + c;
                     kc = kr & 31; kp = kr >> 5; nc = nr & 31; np = nr >> 5; nb = 5; }
        else       { kc = 8*h + e; kp = m; nc = c & 15; np = c >> 4; nb = 4; }
        float gr = 1.f, gi = 0.f;
        for (int j = 0; j < nb; ++j) {
            int w = (a == 0) ? (4 - j) : (a == 1) ? (9 - j) : (13 - j);
            const float* mm = gm + (L*NQ + w)*8;
            const float* ent = mm + (((nc >> j) & 1) * 2 + ((kc >> j) & 1)) * 2;
            float er = ent[0], ei = ent[1];
            float ngr = gr*er - gi*ei, ngi = gr*ei + gi*er;
            gr = ngr; gi = ngi;
        }
        float v = (kp == np) ? gr : (kp ? -gi : gi);
        B[((L*18 + fi)*64 + lane)*8 + e] = (_Float16)v;
    }
}

// ---- the three applies ----
template<int L>
__device__ __forceinline__ void apply0(_Float16* st, const _Float16* B,
                                       int lane, int l31, int h, int w) {
    constexpr int GR = gsrc(L - 1);
    half8 Af[2][4];
    const int rb = lam0(w | (l31 << 4) | (h << 12), 0, GR);
    #pragma unroll
    for (int ss = 0; ss < 2; ++ss)
        #pragma unroll
        for (int m = 0; m < 4; ++m)
            Af[ss][m] = *(const half8*)(st + (rb ^ lam0((ss << 3) | ((m & 1) << 13), m >> 1, GR)));
    __syncthreads();
    half8 Bf[8];
    #pragma unroll
    for (int f = 0; f < 8; ++f)
        Bf[f] = *(const half8*)(B + ((L*18 + f)*64 + lane)*8);
    const int wb = lam1(w | (h << 6) | (l31 << 9), 0);
    #pragma unroll
    for (int ss = 0; ss < 2; ++ss)
        #pragma unroll
        for (int t = 0; t < 2; ++t) {
            f32x16 acc;
            #pragma unroll
            for (int j = 0; j < 16; ++j) acc[j] = 0.f;
            #pragma unroll
            for (int m = 0; m < 4; ++m)
                acc = __builtin_amdgcn_mfma_f32_32x32x16_f16(Af[ss][m], Bf[t*4+m], acc, 0, 0, 0);
            #pragma unroll
            for (int q = 0; q < 4; ++q) {
                uint2 wv;
                wv.x = __builtin_bit_cast(unsigned, __builtin_amdgcn_cvt_pkrtz(acc[4*q+0], acc[4*q+1]));
                wv.y = __builtin_bit_cast(unsigned, __builtin_amdgcn_cvt_pkrtz(acc[4*q+2], acc[4*q+3]));
                *(uint2*)(st + (wb ^ lam1((ss << 3) | ((q & 1) << 7) | ((q >> 1) << 8), t))) = wv;
            }
        }
    __syncthreads();
}

template<int L>
__device__ __forceinline__ void apply1(_Float16* st, const _Float16* B,
                                       int lane, int l31, int h, int w) {
    half8 Af[2][4];
    const int rb = lam1((l31 & 15) | (h << 7) | (w << 9) | (((l31 >> 4) & 1) << 13), 0);
    #pragma unroll
    for (int ss = 0; ss < 2; ++ss)
        #pragma unroll
        for (int m = 0; m < 4; ++m)
            Af[ss][m] = *(const half8*)(st + (rb ^ lam1((ss << 12) | ((m & 1) << 8), m >> 1)));
    __syncthreads();
    half8 Bf[8];
    #pragma unroll
    for (int f = 0; f < 8; ++f)
        Bf[f] = *(const half8*)(B + ((L*18 + 8 + f)*64 + lane)*8);
    const int wb = lam2((h << 2) | (l31 << 4) | (w << 9), 0);
    #pragma unroll
    for (int ss = 0; ss < 2; ++ss)
        #pragma unroll
        for (int t = 0; t < 2; ++t) {
            f32x16 acc;
            #pragma unroll
            for (int j = 0; j < 16; ++j) acc[j] = 0.f;
            #pragma unroll
            for (int m = 0; m < 4; ++m)
                acc = __builtin_amdgcn_mfma_f32_32x32x16_f16(Af[ss][m], Bf[t*4+m], acc, 0, 0, 0);
            #pragma unroll
            for (int q = 0; q < 4; ++q) {
                uint2 wv;
                wv.x = __builtin_bit_cast(unsigned, __builtin_amdgcn_cvt_pkrtz(acc[4*q+0], acc[4*q+1]));
                wv.y = __builtin_bit_cast(unsigned, __builtin_amdgcn_cvt_pkrtz(acc[4*q+2], acc[4*q+3]));
                *(uint2*)(st + (wb ^ lam2((ss << 12) | ((q & 1) << 3) | ((q >> 1) << 13), t))) = wv;
            }
        }
    __syncthreads();
}

template<int L>
__device__ __forceinline__ void apply2(_Float16* st, const _Float16* B,
                                       int lane, int l31, int h, int w) {
    constexpr int GW = find_g0(L);
    half8 Af[4][2];
    const int rb = lam2((h << 3) | (w << 4) | (l31 << 9), 0);
    #pragma unroll
    for (int ss = 0; ss < 4; ++ss)
        #pragma unroll
        for (int m = 0; m < 2; ++m)
            Af[ss][m] = *(const half8*)(st + (rb ^ lam2(ss << 7, m)));
    __syncthreads();
    half8 Bf[2];
    #pragma unroll
    for (int f = 0; f < 2; ++f)
        Bf[f] = *(const half8*)(B + ((L*18 + 16 + f)*64 + lane)*8);
    // scatter base from lane bits (all deltas constexpr via linearity)
    constexpr int C0 = lam0(ring_F(L, 1), 0, GW);
    constexpr int C1 = lam0(ring_F(L, 2), 0, GW);
    constexpr int C2 = lam0(ring_F(L, 4), 0, GW);
    constexpr int C3 = lam0(ring_F(L, 8), 0, GW);
    constexpr int CP = lam0(0, 1, GW);
    constexpr int CH = lam0(ring_F(L, 1 << 11), 0, GW);
    constexpr int CW0 = lam0(ring_F(L, 1 << 4), 0, GW);
    constexpr int CW1 = lam0(ring_F(L, 1 << 5), 0, GW);
    constexpr int CW2 = lam0(ring_F(L, 1 << 6), 0, GW);
    constexpr int CS0 = lam0(ring_F(L, 1 << 7), 0, GW);
    constexpr int CS1 = lam0(ring_F(L, 1 << 8), 0, GW);
    constexpr int E9  = lam0(ring_F(L, 1 << 9), 0, GW);
    constexpr int E10 = lam0(ring_F(L, 1 << 10), 0, GW);
    constexpr int E12 = lam0(ring_F(L, 1 << 12), 0, GW);
    constexpr int E13 = lam0(ring_F(L, 1 << 13), 0, GW);
    int wb = ((l31 & 1) ? C0 : 0) ^ ((l31 & 2) ? C1 : 0) ^ ((l31 & 4) ? C2 : 0)
           ^ ((l31 & 8) ? C3 : 0) ^ ((l31 & 16) ? CP : 0) ^ (h ? CH : 0)
           ^ ((w & 1) ? CW0 : 0) ^ ((w & 2) ? CW1 : 0) ^ ((w & 4) ? CW2 : 0);
    #pragma unroll
    for (int ss = 0; ss < 4; ++ss) {
        f32x16 acc;
        #pragma unroll
        for (int j = 0; j < 16; ++j) acc[j] = 0.f;
        acc = __builtin_amdgcn_mfma_f32_32x32x16_f16(Af[ss][0], Bf[0], acc, 0, 0, 0);
        acc = __builtin_amdgcn_mfma_f32_32x32x16_f16(Af[ss][1], Bf[1], acc, 0, 0, 0);
        const int ws_ = wb ^ ((ss & 1) ? CS0 : 0) ^ ((ss & 2) ? CS1 : 0);
        #pragma unroll
        for (int r = 0; r < 16; ++r) {
            int wa = ws_ ^ ((r & 1) ? E9 : 0) ^ ((r & 2) ? E10 : 0)
                         ^ ((r & 4) ? E12 : 0) ^ ((r & 8) ? E13 : 0);
            st[wa] = (_Float16)acc[r];
        }
    }
    __syncthreads();
}

template<int L>
__device__ __forceinline__ void do_layer(_Float16* st, const _Float16* B,
                                         int lane, int l31, int h, int w) {
    apply0<L>(st, B, lane, l31, h, w);
    apply1<L>(st, B, lane, l31, h, w);
    apply2<L>(st, B, lane, l31, h, w);
    if constexpr (L < NL - 1) do_layer<L+1>(st, B, lane, l31, h, w);
}

__global__ void __launch_bounds__(NT, 4)
qsim_kernel(const float* __restrict__ x, const _Float16* __restrict__ B,
            float* __restrict__ out)
{
    __shared__ _Float16 st[32768];
    const int tid = threadIdx.x;
    const int lane = tid & 63, wid = tid >> 6;
    const int l31 = lane & 31, h = lane >> 5;
    const float* xb = x + blockIdx.x * NQ;

    // ---- product-state init, written directly in Lam0^GINIT as b128s ----
    // thread-fixed amp bits: a0-2 = wid (wires 13,12,11), a3 = h (wire 10),
    // a4-8 = l31 (wires 9..5); per-element: a9-11 = e (wires 4,3,2),
    // a12 (wire 1), a13 (wire 0).
    {
        float cr = 1.f, ci = 0.f;
        #pragma unroll
        for (int bb = 0; bb < 3; ++bb) {
            float s, c; __sincosf(0.5f * xb[13 - bb], &s, &c);
            if ((wid >> bb) & 1) { float nr = s*ci, ni = -s*cr; cr = nr; ci = ni; }
            else                 { cr *= c; ci *= c; }
        }
        {
            float s, c; __sincosf(0.5f * xb[10], &s, &c);
            if (h) { float nr = s*ci, ni = -s*cr; cr = nr; ci = ni; }
            else   { cr *= c; ci *= c; }
        }
        #pragma unroll
        for (int bb = 0; bb < 5; ++bb) {
            float s, c; __sincosf(0.5f * xb[9 - bb], &s, &c);
            if ((l31 >> bb) & 1) { float nr = s*ci, ni = -s*cr; cr = nr; ci = ni; }
            else                 { cr *= c; ci *= c; }
        }
        float es[3], ec[3];
        #pragma unroll
        for (int bb = 0; bb < 3; ++bb) __sincosf(0.5f * xb[4 - bb], &es[bb], &ec[bb]);
        float s1, c1, s0, c0;
        __sincosf(0.5f * xb[1], &s1, &c1);
        __sincosf(0.5f * xb[0], &s0, &c0);
        const int ib = lam0(wid | (h << 3) | (l31 << 4), 0, GINIT);
        #pragma unroll
        for (int j2 = 0; j2 < 4; ++j2) {
            float dr = cr, di = ci;
            if (j2 & 1) { float nr = s1*di, ni = -s1*dr; dr = nr; di = ni; }
            else        { dr *= c1; di *= c1; }
            if (j2 >> 1) { float nr = s0*di, ni = -s0*dr; dr = nr; di = ni; }
            else         { dr *= c0; di *= c0; }
            half8 R, I;
            #pragma unroll
            for (int e = 0; e < 8; ++e) {
                float rr = dr, ii = di;
                #pragma unroll
                for (int bb = 0; bb < 3; ++bb) {
                    if ((e >> bb) & 1) { float nr = es[bb]*ii, ni = -es[bb]*rr; rr = nr; ii = ni; }
                    else               { rr *= ec[bb]; ii *= ec[bb]; }
                }
                R[e] = (_Float16)rr; I[e] = (_Float16)ii;
            }
            int da = ((j2 & 1) << 12) | ((j2 >> 1) << 13);
            *(half8*)(st + (ib ^ lam0(da, 0, GINIT))) = R;
            *(half8*)(st + (ib ^ lam0(da, 1, GINIT))) = I;
        }
    }
    __syncthreads();

    do_layer<0>(st, B, lane, l31, h, wid);

    // ---- <Z0>: read via the apply0 pattern on Lam0^{G5}; sign = a13 = m0 ----
    {
        constexpr int G5 = find_g0(NL - 1);
        const int rb = lam0(wid | (l31 << 4) | (h << 12), 0, G5);
        float acc = 0.f;
        #pragma unroll
        for (int ss = 0; ss < 2; ++ss)
            #pragma unroll
            for (int m0 = 0; m0 < 2; ++m0) {
                half8 re = *(const half8*)(st + (rb ^ lam0((ss << 3) | (m0 << 13), 0, G5)));
                half8 im = *(const half8*)(st + (rb ^ lam0((ss << 3) | (m0 << 13), 1, G5)));
                float s = 0.f;
                #pragma unroll
                for (int e = 0; e < 8; ++e) {
                    float r = (float)re[e], iv = (float)im[e];
                    s += r*r + iv*iv;
                }
                acc += m0 ? -s : s;
            }
        #pragma unroll
        for (int off = 32; off > 0; off >>= 1) acc += __shfl_down(acc, off, 64);
        __syncthreads();
        float* f = (float*)st;
        if ((tid & 63) == 0) f[tid >> 6] = acc;
        __syncthreads();
        if (tid == 0) {
            float s = 0.f;
            #pragma unroll
            for (int w = 0; w < NT/64; ++w) s += f[w];
            out[blockIdx.x] = s;
        }
    }
}

extern "C" void kernel_launch(void* const* d_in, const int* in_sizes, int n_in,
                              void* d_out, int out_size, void* d_ws, size_t ws_size,
                              hipStream_t stream) {
    const float* x = (const float*)d_in[0];   // (1024, 14) float32
    const float* w = (const float*)d_in[1];   // (6, 14, 3) float32
    float* out = (float*)d_out;               // (1024,) float32
    float* gm = (float*)d_ws;                 // 84*8 floats of 2x2 rot matrices
    _Float16* B = (_Float16*)((char*)d_ws + 4096);  // 6*18*64*8 halfs of B-frags

    prep_kernel<<<1, 128, 0, stream>>>(w, gm);
    prep2_kernel<<<27, 256, 0, stream>>>(gm, B);
    qsim_kernel<<<BATCH, NT, 0, stream>>>(x, B, out);
}